// Round 1
// baseline (281.684 us; speedup 1.0000x reference)
//
#include <hip/hip_runtime.h>

#define BIGF 1e8f
static constexpr int NSEQ = 512;
static constexpr int BAND = 50;
static constexpr int NB = 32;

// One workgroup (= one wave, 64 lanes) per DP problem.
// k in [0,96): k&31 = batch, k>>5 = type (0: xy, 1: xx, 2: yy).
// Banded soft-DTW wavefront over anti-diagonals; two rotating LDS diagonal
// buffers indexed by row i (+1 offset so index 0 is the i=-1 boundary = BIG).
__global__ __launch_bounds__(64) void softdtw_band_kernel(
    const float* __restrict__ x, const float* __restrict__ y,
    float* __restrict__ ws)
{
  const int k = blockIdx.x;
  const int batch = k & (NB - 1);
  const int type = k >> 5;
  const float* Aseq = (type == 2) ? y : x;
  const float* Bseq = (type == 1) ? x : y;
  Aseq += (size_t)batch * NSEQ * 4;
  Bseq += (size_t)batch * NSEQ * 4;

  __shared__ float4 sa[NSEQ];
  __shared__ float4 sb[NSEQ];
  __shared__ float rbuf0[NSEQ + 2];
  __shared__ float rbuf1[NSEQ + 2];

  const int t = threadIdx.x;
  #pragma unroll
  for (int i = 0; i < NSEQ / 64; ++i) {
    sa[t + i * 64] = ((const float4*)Aseq)[t + i * 64];
    sb[t + i * 64] = ((const float4*)Bseq)[t + i * 64];
  }
  for (int i = t; i < NSEQ + 2; i += 64) { rbuf0[i] = BIGF; rbuf1[i] = BIGF; }
  __syncthreads();

  // d = 0: R[0,0] = D(0,0) (softmin over {BIG,BIG,0} == 0).
  if (t == 0) {
    float4 a = sa[0], b = sb[0];
    float dx = a.x - b.x, dy = a.y - b.y, dz = a.z - b.z, dw = a.w - b.w;
    rbuf0[1] = dx * dx + dy * dy + dz * dz + dw * dw;
  }
  __syncthreads();

  const float K1 = 0.721347520444482f;  // 1/(gamma*ln2), gamma=2
  const float K2 = 1.386294361119891f;  // gamma*ln2

  for (int d = 1; d <= 2 * NSEQ - 2; ++d) {
    float* rc = (d & 1) ? rbuf1 : rbuf0;  // will hold diag d; currently holds d-2
    float* rp = (d & 1) ? rbuf0 : rbuf1;  // holds diag d-1
    const int ilo = max(max(0, d - (NSEQ - 1)), max(0, d - BAND + 1) >> 1);
    const int ihi = min(min(NSEQ - 1, d), (d + BAND) >> 1);
    const int i = ilo + t;
    const bool active = (i <= ihi);
    float up = BIGF, left = BIGF, diag = BIGF, dv = 0.0f;
    if (active) {
      const int j = d - i;
      float4 a = sa[i];
      float4 b = sb[j];
      float dx = a.x - b.x, dy = a.y - b.y, dz = a.z - b.z, dw = a.w - b.w;
      dv = dx * dx + dy * dy + dz * dz + dw * dw;
      left = rp[i + 1];  // R[i,   j-1]  (diag d-1, row i)
      up   = rp[i];      // R[i-1, j  ]  (diag d-1, row i-1)
      diag = rc[i];      // R[i-1, j-1]  (diag d-2, row i-1)
    }
    __syncthreads();  // all reads of rc done before anyone overwrites it
    if (active) {
      float m = fminf(fminf(up, left), diag);
      float s = __builtin_exp2f((m - up) * K1)
              + __builtin_exp2f((m - left) * K1)
              + __builtin_exp2f((m - diag) * K1);
      rc[i + 1] = dv + m - K2 * __builtin_log2f(s);
      if (i == ihi) rc[i + 2] = BIGF;  // upper boundary for future readers
    }
    if (t == 0) rc[ilo] = BIGF;        // lower boundary for future readers
    __syncthreads();
  }

  // Final diag d=1022 is even -> rbuf0; row 511 at storage index 512.
  if (t == 0) ws[k] = rbuf0[NSEQ];
}

__global__ void softdtw_combine_kernel(const float* __restrict__ ws,
                                       float* __restrict__ out) {
  int b = threadIdx.x;
  if (b < NB) out[b] = ws[b] - 0.5f * (ws[NB + b] + ws[2 * NB + b]);
}

extern "C" void kernel_launch(void* const* d_in, const int* in_sizes, int n_in,
                              void* d_out, int out_size, void* d_ws, size_t ws_size,
                              hipStream_t stream) {
  const float* x = (const float*)d_in[0];
  const float* y = (const float*)d_in[1];
  float* ws = (float*)d_ws;
  float* out = (float*)d_out;
  softdtw_band_kernel<<<3 * NB, 64, 0, stream>>>(x, y, ws);
  softdtw_combine_kernel<<<1, 64, 0, stream>>>(ws, out);
}

// Round 3
// 155.782 us; speedup vs baseline: 1.8082x; 1.8082x over previous
//
#include <hip/hip_runtime.h>

#define BIGF 1e8f
static constexpr int NSEQ = 512;
static constexpr int BAND = 50;
static constexpr int NB = 32;

// lane l <- lane (l-1)&63 : DPP wavefront rotate-RIGHT-by-1 (gfx9 ctrl 0x13C,
// WF_ROR1). NB: AMD "shift/rotate right" = data moves to higher lanes, i.e.
// each lane reads from the lane one LOWER (the __shfl_up direction).
__device__ __forceinline__ float rotup1(float v) {
  return __int_as_float(__builtin_amdgcn_update_dpp(
      0, __float_as_int(v), 0x13C, 0xf, 0xf, false));
}

// One wave per DP problem. k&31 = batch, k>>5 = type (0:xy, 1:xx, 2:yy).
// Row i lives on lane i&63; diagonals kept in registers:
//   r1  = masked diag d-1 (BIG outside the active window)
//   upp = rot1(masked diag d-2)  ( == "up" from the previous step )
// Per step: up = rot1(r1); diag = upp; left = r1. No barriers, no guards:
// inactive lanes hold BIG, and the one-lane-per-step row jump (i += 64 when
// i < ilo) leaves exactly the right stale value in the rotate chain.
__global__ __launch_bounds__(64) void softdtw_band_kernel(
    const float* __restrict__ x, const float* __restrict__ y,
    float* __restrict__ ws)
{
  const int k = blockIdx.x;
  const int batch = k & (NB - 1);
  const int type = k >> 5;
  const float* Aseq = (type == 2 ? y : x) + (size_t)batch * NSEQ * 4;
  const float* Bseq = (type == 1 ? x : y) + (size_t)batch * NSEQ * 4;

  __shared__ float4 sa[NSEQ];
  __shared__ float4 sb[NSEQ];

  const int l = threadIdx.x;
  #pragma unroll
  for (int q = 0; q < NSEQ / 64; ++q) {
    sa[l + q * 64] = ((const float4*)Aseq)[l + q * 64];
    sb[l + q * 64] = ((const float4*)Bseq)[l + q * 64];
  }
  __syncthreads();

  const float K1 = 0.721347520444482f;  // 1/(gamma*ln2), gamma=2
  const float K2 = 1.386294361119891f;  // gamma*ln2

  // d = 0 seed: R[0,0] = D(0,0)
  float4 A0 = sa[0], B0 = sb[0];
  float e0 = A0.x - B0.x, e1 = A0.y - B0.y, e2 = A0.z - B0.z, e3 = A0.w - B0.w;
  float dv00 = ((e0 * e0 + e1 * e1) + (e2 * e2 + e3 * e3));
  float r1 = (l == 0) ? dv00 : BIGF;
  float upp = BIGF;

  int i = l;  // row of this lane; invariant i = ilo + ((l - ilo) & 63)

  // 3-deep prefetch pipeline (named slots, fully register-resident).
  // Slots hold a[i(d)], b[j(d)] for d = 1,2,3 (ilo=0 there, so i=l).
  float4 av0, av1, av2, bv0, bv1, bv2;
  av0 = sa[i]; av1 = av0; av2 = av0;
  bv0 = sb[max(0, 1 - l)];
  bv1 = sb[max(0, 2 - l)];
  bv2 = sb[max(0, 3 - l)];

#define STEP(D, AV, BV)                                                         \
  {                                                                             \
    const int d_ = (D);                                                         \
    const int ilo_ = max(max(0, d_ - (NSEQ - 1)), max(0, d_ - (BAND - 1)) >> 1);\
    const int ihi_ = min(min(NSEQ - 1, d_), (d_ + BAND) >> 1);                  \
    i += (i < ilo_) ? 64 : 0;                                                   \
    float ddx = AV.x - BV.x, ddy = AV.y - BV.y,                                 \
          ddz = AV.z - BV.z, ddw = AV.w - BV.w;                                 \
    float dv = ddx * ddx;                                                       \
    dv = __builtin_fmaf(ddy, ddy, dv);                                          \
    dv = __builtin_fmaf(ddz, ddz, dv);                                          \
    dv = __builtin_fmaf(ddw, ddw, dv);                                          \
    float up = rotup1(r1);                                                      \
    float dg = upp;                                                             \
    float left = r1;                                                            \
    float mn = fminf(fminf(up, left), dg);                                      \
    float mk = mn * K1;                                                         \
    float ssum = __builtin_exp2f(__builtin_fmaf(-K1, up, mk))                   \
               + __builtin_exp2f(__builtin_fmaf(-K1, left, mk))                 \
               + __builtin_exp2f(__builtin_fmaf(-K1, dg, mk));                  \
    float rr = __builtin_fmaf(-K2, __builtin_log2f(ssum), mn + dv);             \
    r1 = (i <= ihi_) ? rr : BIGF;                                               \
    upp = up;                                                                   \
    const int d3_ = d_ + 3;                                                     \
    const int ilo3_ =                                                           \
        max(max(0, d3_ - (NSEQ - 1)), max(0, d3_ - (BAND - 1)) >> 1);           \
    int i3_ = ilo3_ + ((l - ilo3_) & 63);                                       \
    int j3_ = d3_ - i3_;                                                        \
    i3_ = min(i3_, NSEQ - 1);                                                   \
    j3_ = max(0, min(NSEQ - 1, j3_));                                           \
    AV = sa[i3_];                                                               \
    BV = sb[j3_];                                                               \
  }

  // d = 1 .. 1023 (1023 = 3*341 iterations, exact). Step d=1023 has no
  // active cells; its up = rot1(diag 1022) moves lane 63's R[511,511]
  // into lane 0 of upp.
  for (int mm = 0; mm < 341; ++mm) {
    const int d = 3 * mm + 1;
    STEP(d, av0, bv0);
    STEP(d + 1, av1, bv1);
    STEP(d + 2, av2, bv2);
  }
#undef STEP

  if (l == 0) ws[k] = upp;
}

__global__ void softdtw_combine_kernel(const float* __restrict__ ws,
                                       float* __restrict__ out) {
  int b = threadIdx.x;
  if (b < NB) out[b] = ws[b] - 0.5f * (ws[NB + b] + ws[2 * NB + b]);
}

extern "C" void kernel_launch(void* const* d_in, const int* in_sizes, int n_in,
                              void* d_out, int out_size, void* d_ws, size_t ws_size,
                              hipStream_t stream) {
  const float* x = (const float*)d_in[0];
  const float* y = (const float*)d_in[1];
  float* ws = (float*)d_ws;
  float* out = (float*)d_out;
  softdtw_band_kernel<<<3 * NB, 64, 0, stream>>>(x, y, ws);
  softdtw_combine_kernel<<<1, 64, 0, stream>>>(ws, out);
}